// Round 7
// baseline (49.941 us; speedup 1.0000x reference)
//
#include <hip/hip_runtime.h>
#include <math.h>

#define NROWS 8192
#define NK    4096
#define NE    64
#define NWV   16    // waves per block = K segments of 256

typedef _Float16 f16x8 __attribute__((ext_vector_type(8)));  // 4 VGPRs
typedef float    f32x4 __attribute__((ext_vector_type(4)));

// ---------------------------------------------------------------------------
// Kernel 0: arrange W into MFMA-fragment-linear f16 hi/lo arrays; zero imp
// and the block-completion counter. (fragment layout verified rounds 4-6)
// Element ((ksg*4 + nt)*64 + lane)*8 + j holds
//   f16( W[nt*16 + (lane&15)][ksg*32 + (lane>>4)*8 + j] ), ksg = 0..127.
// ---------------------------------------------------------------------------
__global__ __launch_bounds__(256) void k_prep(const float* __restrict__ W,
                                              _Float16* __restrict__ Whi,
                                              _Float16* __restrict__ Wlo,
                                              float* __restrict__ imp,
                                              unsigned* __restrict__ cnt) {
  const int idx = blockIdx.x * 256 + threadIdx.x;   // 0 .. 262143
  if (idx < NE) imp[idx] = 0.f;
  if (idx == NE) *cnt = 0u;
  const int j    = idx & 7;
  const int lane = (idx >> 3) & 63;
  const int nt   = (idx >> 9) & 3;
  const int ksg  = idx >> 11;                        // 0..127
  const int e = nt * 16 + (lane & 15);
  const int k = ksg * 32 + (lane >> 4) * 8 + j;
  const float w = W[(size_t)e * NK + k];
  const _Float16 wh = (_Float16)w;
  const _Float16 wl = (_Float16)(w - (float)wh);
  Whi[idx] = wh;
  Wlo[idx] = wl;
}

// ---------------------------------------------------------------------------
// Kernel 1 (FULLY FUSED): 32 rows x full K per block; GEMM partials -> LDS ->
// 16-way tree reduce -> softmax/top-2/renorm -> outputs; importance atomics;
// LAST block computes the aux loss (no separate k_aux launch).
// grid = 256 (1 block/CU), block = 1024 (16 waves = 4/SIMD, 2x round 6 TLP).
// Wave wv: TWO 16-row M-tiles (rows blk*32 .. +32) x K-seg [wv*256, +256),
// B-fragments shared between the M-tiles (structure verified rounds 5-6).
// ---------------------------------------------------------------------------
__global__ __launch_bounds__(1024, 4) void k_fused(const float* __restrict__ x,
                                                   const _Float16* __restrict__ Whi,
                                                   const _Float16* __restrict__ Wlo,
                                                   float* __restrict__ out,
                                                   float* __restrict__ imp,
                                                   unsigned* __restrict__ cnt) {
  __shared__ float plds[NWV][32][64];   // 128 KB partial logits
  __shared__ float logit[32][64];       // 8 KB reduced logits
  __shared__ float simp[NWV][64];       // 4 KB importance partials
  __shared__ int   lastflag;

  const int tid  = threadIdx.x;
  const int lane = tid & 63;
  const int wv   = __builtin_amdgcn_readfirstlane(tid >> 6);  // 0..15 = K-seg
  const int l15  = lane & 15;
  const int lhi  = lane >> 4;
  const int rbase = blockIdx.x * 32;
  const int k0    = wv * 256;

  const float* __restrict__ xp0 = x + (size_t)(rbase + l15) * NK + k0 + lhi * 8;
  const float* __restrict__ xp1 = xp0 + (size_t)16 * NK;

  f32x4 acc0[4], acc1[4];
#pragma unroll
  for (int nt = 0; nt < 4; ++nt) {
    acc0[nt] = (f32x4){0.f, 0.f, 0.f, 0.f};
    acc1[nt] = (f32x4){0.f, 0.f, 0.f, 0.f};
  }

#pragma unroll 1
  for (int ks = 0; ks < 8; ++ks) {   // 8 K-steps of 32
    const float4 a0 = *(const float4*)(xp0 + ks * 32);
    const float4 a1 = *(const float4*)(xp0 + ks * 32 + 4);
    const float4 b0 = *(const float4*)(xp1 + ks * 32);
    const float4 b1 = *(const float4*)(xp1 + ks * 32 + 4);
    f16x8 ah, al, bh, bl;
    ah[0] = (_Float16)a0.x; al[0] = (_Float16)(a0.x - (float)ah[0]);
    ah[1] = (_Float16)a0.y; al[1] = (_Float16)(a0.y - (float)ah[1]);
    ah[2] = (_Float16)a0.z; al[2] = (_Float16)(a0.z - (float)ah[2]);
    ah[3] = (_Float16)a0.w; al[3] = (_Float16)(a0.w - (float)ah[3]);
    ah[4] = (_Float16)a1.x; al[4] = (_Float16)(a1.x - (float)ah[4]);
    ah[5] = (_Float16)a1.y; al[5] = (_Float16)(a1.y - (float)ah[5]);
    ah[6] = (_Float16)a1.z; al[6] = (_Float16)(a1.z - (float)ah[6]);
    ah[7] = (_Float16)a1.w; al[7] = (_Float16)(a1.w - (float)ah[7]);
    bh[0] = (_Float16)b0.x; bl[0] = (_Float16)(b0.x - (float)bh[0]);
    bh[1] = (_Float16)b0.y; bl[1] = (_Float16)(b0.y - (float)bh[1]);
    bh[2] = (_Float16)b0.z; bl[2] = (_Float16)(b0.z - (float)bh[2]);
    bh[3] = (_Float16)b0.w; bl[3] = (_Float16)(b0.w - (float)bh[3]);
    bh[4] = (_Float16)b1.x; bl[4] = (_Float16)(b1.x - (float)bh[4]);
    bh[5] = (_Float16)b1.y; bl[5] = (_Float16)(b1.y - (float)bh[5]);
    bh[6] = (_Float16)b1.z; bl[6] = (_Float16)(b1.z - (float)bh[6]);
    bh[7] = (_Float16)b1.w; bl[7] = (_Float16)(b1.w - (float)bh[7]);

    const int gk = wv * 8 + ks;       // global 32-k group, 0..127
    const size_t boff = ((size_t)(gk * 4) * 64 + lane) * 8;
    f16x8 wh_[4], wl_[4];
#pragma unroll
    for (int nt = 0; nt < 4; ++nt) {
      wh_[nt] = *(const f16x8*)(Whi + boff + nt * 512);
      wl_[nt] = *(const f16x8*)(Wlo + boff + nt * 512);
    }
#pragma unroll
    for (int nt = 0; nt < 4; ++nt) {
      acc0[nt] = __builtin_amdgcn_mfma_f32_16x16x32_f16(ah, wh_[nt], acc0[nt], 0, 0, 0);
      acc1[nt] = __builtin_amdgcn_mfma_f32_16x16x32_f16(bh, wh_[nt], acc1[nt], 0, 0, 0);
    }
#pragma unroll
    for (int nt = 0; nt < 4; ++nt) {
      acc0[nt] = __builtin_amdgcn_mfma_f32_16x16x32_f16(ah, wl_[nt], acc0[nt], 0, 0, 0);
      acc1[nt] = __builtin_amdgcn_mfma_f32_16x16x32_f16(bh, wl_[nt], acc1[nt], 0, 0, 0);
    }
#pragma unroll
    for (int nt = 0; nt < 4; ++nt) {
      acc0[nt] = __builtin_amdgcn_mfma_f32_16x16x32_f16(al, wh_[nt], acc0[nt], 0, 0, 0);
      acc1[nt] = __builtin_amdgcn_mfma_f32_16x16x32_f16(bl, wh_[nt], acc1[nt], 0, 0, 0);
    }
  }

  // ---- epilogue to LDS: D col = lane&15, row = (lane>>4)*4 + reg ----
#pragma unroll
  for (int nt = 0; nt < 4; ++nt)
#pragma unroll
    for (int r = 0; r < 4; ++r) {
      plds[wv][lhi * 4 + r][nt * 16 + l15]      = acc0[nt][r];
      plds[wv][16 + lhi * 4 + r][nt * 16 + l15] = acc1[nt][r];
    }
  __syncthreads();

  // ---- 16-seg pairwise tree reduce: 2048 elems, 1024 threads x 2 ----
#pragma unroll
  for (int i = 0; i < 2; ++i) {
    const int elem = tid + i * 1024;     // 0..2047
    const int row  = elem >> 6;
    const int col  = elem & 63;
    float s[8];
#pragma unroll
    for (int p = 0; p < 8; ++p)
      s[p] = plds[2 * p][row][col] + plds[2 * p + 1][row][col];
    logit[row][col] = (((s[0] + s[1]) + (s[2] + s[3])) +
                       ((s[4] + s[5]) + (s[6] + s[7])));
  }
  __syncthreads();

  // ---- softmax/top-2/renorm: wave wv handles rows wv*2 .. +2 --------------
  float impacc = 0.f;
#pragma unroll 1
  for (int i = 0; i < 2; ++i) {
    const int rl  = wv * 2 + i;
    const int row = rbase + rl;
    const float lg = logit[rl][lane];

    float m = lg;
#pragma unroll
    for (int d = 1; d < 64; d <<= 1) m = fmaxf(m, __shfl_xor(m, d));
    float p = expf(lg - m);
    float s = p;
#pragma unroll
    for (int d = 1; d < 64; d <<= 1) s += __shfl_xor(s, d);
    const float gate = p / s;
    impacc += gate;

    const unsigned long long key =
        ((unsigned long long)__float_as_uint(gate) << 32) | (unsigned)(63 - lane);
    unsigned long long k1 = key;
#pragma unroll
    for (int d = 1; d < 64; d <<= 1) {
      unsigned long long o = __shfl_xor(k1, d);
      if (o > k1) k1 = o;
    }
    const int e1 = 63 - (int)(k1 & 63ull);
    unsigned long long k2 = (lane == e1) ? 0ull : key;
#pragma unroll
    for (int d = 1; d < 64; d <<= 1) {
      unsigned long long o = __shfl_xor(k2, d);
      if (o > k2) k2 = o;
    }
    const int e2 = 63 - (int)(k2 & 63ull);

    if (lane == 0) {
      const float g1 = __uint_as_float((unsigned)(k1 >> 32));
      const float g2 = __uint_as_float((unsigned)(k2 >> 32));
      const float tt  = expf(g2 - g1);          // g1 >= g2
      const float inv = 1.f / (1.f + tt);
      out[(size_t)row * 2]     = inv;
      out[(size_t)row * 2 + 1] = tt * inv;
      out[(size_t)NROWS * 2 + row * 2]     = (float)e1;
      out[(size_t)NROWS * 2 + row * 2 + 1] = (float)e2;
    }
  }
  simp[wv][lane] = impacc;
  __syncthreads();

  // ---- importance atomics (device scope), then last-block aux -------------
  if (tid < NE) {
    float v = 0.f;
#pragma unroll
    for (int p = 0; p < 8; ++p) v += simp[2 * p][tid] + simp[2 * p + 1][tid];
    atomicAdd(&imp[tid], v);
  }
  __syncthreads();   // drains vmcnt: this block's imp atomics are complete

  if (tid == 0) {
    const unsigned old = atomicAdd(cnt, 1u);
    lastflag = (old == 255u) ? 1 : 0;
  }
  __syncthreads();

  if (lastflag && tid < NE) {
    // device-scope read of fully-accumulated imp (atomic read bypasses caches)
    const float v = atomicAdd(&imp[tid], 0.f);
    float s = v;
#pragma unroll
    for (int d = 1; d < 64; d <<= 1) s += __shfl_xor(s, d);
    const float mean = s / 64.f;
    const float dv = v - mean;
    float sq = dv * dv;
#pragma unroll
    for (int d = 1; d < 64; d <<= 1) sq += __shfl_xor(sq, d);
    const float stdv = sqrtf(sq / 63.f);  // unbiased (E-1)
    const float r = stdv / (mean + 1e-6f);
    if (tid == 0) out[(size_t)NROWS * 4] = r * r;  // d_out[32768]
  }
}

// ---------------------------------------------------------------------------
extern "C" void kernel_launch(void* const* d_in, const int* in_sizes, int n_in,
                              void* d_out, int out_size, void* d_ws, size_t ws_size,
                              hipStream_t stream) {
  const float* x = (const float*)d_in[0];
  const float* W = (const float*)d_in[1];
  float* out  = (float*)d_out;
  _Float16* Whi = (_Float16*)d_ws;                 // 512 KB
  _Float16* Wlo = Whi + (size_t)NE * NK;           // 512 KB
  float* imp  = (float*)(Wlo + (size_t)NE * NK);   // 64 f32
  unsigned* cnt = (unsigned*)(imp + NE);           // 1 u32

  hipLaunchKernelGGL(k_prep,  dim3(1024), dim3(256),  0, stream, W, Whi, Wlo, imp, cnt);
  hipLaunchKernelGGL(k_fused, dim3(256),  dim3(1024), 0, stream, x, Whi, Wlo, out, imp, cnt);
}